// Round 2
// baseline (479.047 us; speedup 1.0000x reference)
//
#include <hip/hip_runtime.h>
#include <hip/hip_bf16.h>
#include <math.h>

using bf16 = __hip_bfloat16;
using frag8 = __attribute__((ext_vector_type(8))) short;
using f32x4 = __attribute__((ext_vector_type(4))) float;

#define LEAKY 0.2f
#define BN_EPS 1e-5f
#define NEGBIG -1e30f

__device__ __forceinline__ float lrelu(float z){ return fmaxf(z, LEAKY * z); }
__device__ __forceinline__ float bflo(unsigned u){ return __uint_as_float(u << 16); }
__device__ __forceinline__ float bfhi(unsigned u){ return __uint_as_float(u & 0xffff0000u); }
// pack two floats into bf16 pair (RNE)
__device__ __forceinline__ unsigned pk(float a, float b){
  unsigned ua = __float_as_uint(a), ub = __float_as_uint(b);
  ua += 0x7fffu + ((ua >> 16) & 1u);
  ub += 0x7fffu + ((ub >> 16) & 1u);
  return (ua >> 16) | (ub & 0xffff0000u);
}
// dtype-adaptive load: isbf=1 -> bf16, else fp32
__device__ __forceinline__ float ldf(const void* p, size_t i, int isbf){
  if (isbf) return (float)((const bf16*)p)[i];
  return ((const float*)p)[i];
}

union U4F8 { uint4 u; frag8 f; };

// A-frag loaders: lane m=lane&15 -> node, k0 = s*32 + quad*8, 8 bf16 = 16B
__device__ __forceinline__ frag8 load_a_pairs(const unsigned* __restrict__ X2, int node, int k0){
  U4F8 v; v.u = *((const uint4*)(X2 + (size_t)node*64 + (k0 >> 1))); return v.f;
}
__device__ __forceinline__ frag8 load_a_f32(const float* __restrict__ X, int node, int k0){
  float4 q0 = *((const float4*)(X + (size_t)node*128 + k0));
  float4 q1 = *((const float4*)(X + (size_t)node*128 + k0 + 4));
  U4F8 v; v.u = make_uint4(pk(q0.x,q0.y), pk(q0.z,q0.w), pk(q1.x,q1.y), pk(q1.z,q1.w));
  return v.f;
}

// ------------- cnt zero + total zero + fused input-dtype detector (block 0) ---
__global__ void init_detect(int* cnt, const unsigned short* __restrict__ w1bits,
                            int* flag, int* total, int n){
  int g = blockIdx.x*256 + threadIdx.x;
  if (g < n) cnt[g] = 0;
  if (g == 0) *total = 0;
  if (blockIdx.x == 0){
    __shared__ int cntr;
    if (threadIdx.x == 0) cntr = 0;
    __syncthreads();
    unsigned u = w1bits[threadIdx.x * 2];
    int e = (u >> 7) & 0xff;
    atomicAdd(&cntr, (e >= 64 && e <= 140) ? 1 : 0);
    __syncthreads();
    if (threadIdx.x == 0) *flag = (cntr >= 160) ? 1 : 0;
  }
}

// ------------- degree histogram: coalesced dst read, L2-hot atomics -----------
__global__ void hist(const int* __restrict__ dst, int* cnt, int e, int n){
  int g = blockIdx.x*256 + threadIdx.x;
  if (g < e){
    int d = dst[g];
    if ((unsigned)d < (unsigned)n) atomicAdd(&cnt[d], 1);
  }
}

// ------------- block-scan -> start offsets (order-free segments) + cursor -----
__global__ void csr_scan(const int* __restrict__ cnt, int* start, int* pos,
                         int* total, int n){
  __shared__ int s[256];
  __shared__ int base_s;
  int t = threadIdx.x;
  int g = blockIdx.x*256 + t;
  int v = (g < n) ? cnt[g] : 0;
  s[t] = v;
  __syncthreads();
  for (int off = 1; off < 256; off <<= 1){
    int x = (t >= off) ? s[t-off] : 0;
    __syncthreads();
    s[t] += x;
    __syncthreads();
  }
  if (t == 255) base_s = atomicAdd(total, s[255]);
  __syncthreads();
  if (g < n){
    int st = base_s + s[t] - v;
    start[g] = st;
    pos[g] = st;
  }
}

// ------------- direct scatter: coalesced src/dst reads, cursor atomics --------
__global__ void scatter(const int* __restrict__ src, const int* __restrict__ dst,
                        int* pos, int* col, int e, int n){
  int g = blockIdx.x*256 + threadIdx.x;
  if (g < e){
    int d = dst[g];
    if ((unsigned)d < (unsigned)n){
      int p = atomicAdd(&pos[d], 1);
      col[p] = src[g];
    }
  }
}

// ---------------- MFMA GEMM 128x128 + fused al (layers 1,2) --------------------
__global__ __launch_bounds__(256) void gemm_al_mfma(
    const void* __restrict__ X, int xkind,   // 0 = external input, 1 = packed pairs
    const void* __restrict__ W, const void* __restrict__ Wsrc, const void* __restrict__ Wdst,
    const int* __restrict__ flagp,
    unsigned* __restrict__ H2, float* __restrict__ AL, float* __restrict__ AD,
    int n, int ntiles)
{
  __shared__ unsigned short WT[128*136];   // W^T bf16, stride 136 (bank-stagger)
  const int isbf = *flagp;
  const int t = threadIdx.x;
  if (isbf){
    const unsigned short* W16 = (const unsigned short*)W;
    for (int idx = t; idx < 16384; idx += 256){
      int k = idx >> 7, nn = idx & 127;
      WT[nn*136 + k] = W16[idx];
    }
  } else {
    const float* Wf = (const float*)W;
    for (int idx = t; idx < 16384; idx += 256){
      int k = idx >> 7, nn = idx & 127;
      WT[nn*136 + k] = (unsigned short)(pk(Wf[idx], 0.f) & 0xffffu);
    }
  }
  __syncthreads();
  const int w = t >> 6;          // wave == head
  const int lane = t & 63;
  const int m = lane & 15, quad = lane >> 4;

  frag8 bf[4][2];
  #pragma unroll
  for (int s = 0; s < 4; ++s)
    #pragma unroll
    for (int ct = 0; ct < 2; ++ct){
      int colc = w*32 + ct*16 + m;
      int k0 = s*32 + quad*8;
      U4F8 v; v.u = *((const uint4*)&WT[colc*136 + k0]);
      bf[s][ct] = v.f;
    }
  float avv[2], dvv[2];
  #pragma unroll
  for (int ct = 0; ct < 2; ++ct){
    int colc = w*32 + ct*16 + m;
    avv[ct] = ldf(Wsrc, colc, isbf);
    dvv[ct] = ldf(Wdst, colc, isbf);
  }
  const bool pairs = (xkind == 1) || isbf;  // bf16 rows == packed-pair layout

  for (int tile = blockIdx.x; tile < ntiles; tile += gridDim.x){
    const int mb = tile*16;
    int nodeA = mb + m; if (nodeA >= n) nodeA = n - 1;
    frag8 af[4];
    #pragma unroll
    for (int s = 0; s < 4; ++s){
      int k0 = s*32 + quad*8;
      af[s] = pairs ? load_a_pairs((const unsigned*)X, nodeA, k0)
                    : load_a_f32((const float*)X, nodeA, k0);
    }
    f32x4 acc0 = {0.f,0.f,0.f,0.f}, acc1 = {0.f,0.f,0.f,0.f};
    #pragma unroll
    for (int s = 0; s < 4; ++s){
      acc0 = __builtin_amdgcn_mfma_f32_16x16x32_bf16(af[s], bf[s][0], acc0, 0,0,0);
      acc1 = __builtin_amdgcn_mfma_f32_16x16x32_bf16(af[s], bf[s][1], acc1, 0,0,0);
    }
    #pragma unroll
    for (int r = 0; r < 4; ++r){
      int g = mb + quad*4 + r;
      float v0 = acc0[r], v1 = acc1[r];
      unsigned u0 = pk(v0, __shfl_xor(v0, 1));
      unsigned u1 = pk(v1, __shfl_xor(v1, 1));
      bool ok = g < n;
      if (((lane & 1) == 0) && ok){
        H2[(size_t)g*64 + w*16 + (m >> 1)]     = u0;
        H2[(size_t)g*64 + w*16 + 8 + (m >> 1)] = u1;
      }
      float s1 = v0*avv[0] + v1*avv[1];
      float s2 = v0*dvv[0] + v1*dvv[1];
      s1 += __shfl_xor(s1,1); s1 += __shfl_xor(s1,2); s1 += __shfl_xor(s1,4); s1 += __shfl_xor(s1,8);
      s2 += __shfl_xor(s2,1); s2 += __shfl_xor(s2,2); s2 += __shfl_xor(s2,4); s2 += __shfl_xor(s2,8);
      if (m == 0 && ok){ AL[g*4 + w] = s1; AD[g*4 + w] = s2; }
    }
  }
}

// ---------------- MFMA GEMM 128x40 + fused al (layer 3) -----------------------
__global__ __launch_bounds__(256) void gemm3_mfma(
    const unsigned* __restrict__ X2, const void* __restrict__ W,
    const void* __restrict__ Wsrc, const void* __restrict__ Wdst,
    const int* __restrict__ flagp,
    unsigned* __restrict__ H3, float* __restrict__ AL, float* __restrict__ AD,
    int n, int ntiles)
{
  __shared__ unsigned short WT[48*136];
  const int isbf = *flagp;
  const int t = threadIdx.x;
  for (int idx = t; idx < 128*64; idx += 256){
    int c = idx & 63, k = idx >> 6;
    if (c < 48){
      unsigned short v = 0;
      if (c < 40){
        if (isbf) v = ((const unsigned short*)W)[k*40 + c];
        else      v = (unsigned short)(pk(((const float*)W)[k*40 + c], 0.f) & 0xffffu);
      }
      WT[c*136 + k] = v;
    }
  }
  __syncthreads();
  const int w = t >> 6;
  const int lane = t & 63;
  const int m = lane & 15, quad = lane >> 4;

  frag8 bf[4][3];
  float avv[3], dvv[3];
  #pragma unroll
  for (int ct = 0; ct < 3; ++ct){
    int colc = ct*16 + m;
    #pragma unroll
    for (int s = 0; s < 4; ++s){
      int k0 = s*32 + quad*8;
      U4F8 v; v.u = *((const uint4*)&WT[colc*136 + k0]);
      bf[s][ct] = v.f;
    }
    avv[ct] = (colc < 40) ? ldf(Wsrc, colc, isbf) : 0.f;
    dvv[ct] = (colc < 40) ? ldf(Wdst, colc, isbf) : 0.f;
  }

  for (int tg = blockIdx.x; tg*4 < ntiles; tg += gridDim.x){
    const int tile = tg*4 + w;
    if (tile >= ntiles) continue;
    const int mb = tile*16;
    int nodeA = mb + m; if (nodeA >= n) nodeA = n - 1;
    frag8 af[4];
    #pragma unroll
    for (int s = 0; s < 4; ++s)
      af[s] = load_a_pairs(X2, nodeA, s*32 + quad*8);
    f32x4 acc[3];
    #pragma unroll
    for (int ct = 0; ct < 3; ++ct) acc[ct] = (f32x4){0.f,0.f,0.f,0.f};
    #pragma unroll
    for (int s = 0; s < 4; ++s){
      acc[0] = __builtin_amdgcn_mfma_f32_16x16x32_bf16(af[s], bf[s][0], acc[0], 0,0,0);
      acc[1] = __builtin_amdgcn_mfma_f32_16x16x32_bf16(af[s], bf[s][1], acc[1], 0,0,0);
      acc[2] = __builtin_amdgcn_mfma_f32_16x16x32_bf16(af[s], bf[s][2], acc[2], 0,0,0);
    }
    #pragma unroll
    for (int r = 0; r < 4; ++r){
      int g = mb + quad*4 + r;
      bool ok = g < n;
      float ps = 0.f, pd = 0.f;
      #pragma unroll
      for (int ct = 0; ct < 3; ++ct){
        float v = acc[ct][r];
        ps += v*avv[ct]; pd += v*dvv[ct];
        unsigned u = pk(v, __shfl_xor(v, 1));
        bool stok = ((lane & 1) == 0) && ok && (ct < 2 || m < 8);
        if (stok) H3[(size_t)g*20 + ct*8 + (m >> 1)] = u;
      }
      ps += __shfl_xor(ps,1); ps += __shfl_xor(ps,2); ps += __shfl_xor(ps,4); ps += __shfl_xor(ps,8);
      pd += __shfl_xor(pd,1); pd += __shfl_xor(pd,2); pd += __shfl_xor(pd,4); pd += __shfl_xor(pd,8);
      if (m == 0 && ok){ AL[g] = ps; AD[g] = pd; }
    }
  }
}

// ---- aggregation (layers 1,2): 1 node/wave, 4 edge-subgroups x 16 lanes ------
// subgroup sub handles edges i+sub*2+u; 16 lanes read the full 256B row as uint4.
__global__ __launch_bounds__(256) void agg4(
    const unsigned* __restrict__ H2,
    const float* __restrict__ ALf, const float* __restrict__ ADf,
    const int* __restrict__ cnt, const int* __restrict__ start, const int* __restrict__ col,
    const void* __restrict__ bias, const void* __restrict__ bng, const void* __restrict__ bnb,
    const void* __restrict__ bnm,  const void* __restrict__ bnv,
    const int* __restrict__ flagp,
    unsigned* __restrict__ Hout, int n)
{
  const int isbf = *flagp;
  const int wave = threadIdx.x >> 6;
  const int lane = threadIdx.x & 63;
  const int node = blockIdx.x*4 + wave;
  if (node >= n) return;
  const int sub = lane >> 4;       // edge subgroup 0..3
  const int p = lane & 15;         // word-quad within 256B node row
  const int head = p >> 2;         // 8 channels per lane -> one head
  const float ad = ADf[node*4 + head];
  const int base = start[node], deg = cnt[node];

  float acc[8] = {0.f,0.f,0.f,0.f,0.f,0.f,0.f,0.f};
  float l = 0.f;
  if (sub == 0){                   // self-loop handled by subgroup 0 only
    float e = __expf(lrelu(ALf[node*4 + head] + ad));
    uint4 h = *((const uint4*)(H2 + (size_t)node*64 + p*4));
    l = e;
    acc[0] = e*bflo(h.x); acc[1] = e*bfhi(h.x);
    acc[2] = e*bflo(h.y); acc[3] = e*bfhi(h.y);
    acc[4] = e*bflo(h.z); acc[5] = e*bfhi(h.z);
    acc[6] = e*bflo(h.w); acc[7] = e*bfhi(h.w);
  }

  int i = 0;
  for (; i + 8 <= deg; i += 8){    // 8 edges/iter: 2 per subgroup
    int sv[2]; float av[2]; uint4 hv[2];
    const int eb = base + i + sub*2;
    #pragma unroll
    for (int u = 0; u < 2; ++u){
      int s = col[eb + u];
      sv[u] = ((unsigned)s < (unsigned)n) ? s : 0;
    }
    #pragma unroll
    for (int u = 0; u < 2; ++u) av[u] = ALf[sv[u]*4 + head];
    #pragma unroll
    for (int u = 0; u < 2; ++u) hv[u] = *((const uint4*)(H2 + (size_t)sv[u]*64 + p*4));
    #pragma unroll
    for (int u = 0; u < 2; ++u){
      float e = __expf(lrelu(av[u] + ad));
      l += e;
      acc[0] += e*bflo(hv[u].x); acc[1] += e*bfhi(hv[u].x);
      acc[2] += e*bflo(hv[u].y); acc[3] += e*bfhi(hv[u].y);
      acc[4] += e*bflo(hv[u].z); acc[5] += e*bfhi(hv[u].z);
      acc[6] += e*bflo(hv[u].w); acc[7] += e*bfhi(hv[u].w);
    }
  }
  for (; i < deg; i += 4){         // tail: 1 edge per subgroup, masked
    const int idx = i + sub;
    const bool valid = idx < deg;
    int s = col[valid ? base + idx : base];
    if ((unsigned)s >= (unsigned)n) s = 0;
    float a = ALf[s*4 + head];
    uint4 h = *((const uint4*)(H2 + (size_t)s*64 + p*4));
    float e = valid ? __expf(lrelu(a + ad)) : 0.f;
    l += e;
    acc[0] += e*bflo(h.x); acc[1] += e*bfhi(h.x);
    acc[2] += e*bflo(h.y); acc[3] += e*bfhi(h.y);
    acc[4] += e*bflo(h.z); acc[5] += e*bfhi(h.z);
    acc[6] += e*bflo(h.w); acc[7] += e*bfhi(h.w);
  }

  // merge the 4 subgroup partials (lanes p, p+16, p+32, p+48)
  #pragma unroll
  for (int q = 0; q < 8; ++q){
    acc[q] += __shfl_xor(acc[q], 16);
    acc[q] += __shfl_xor(acc[q], 32);
  }
  l += __shfl_xor(l, 16);
  l += __shfl_xor(l, 32);

  if (sub != 0) return;
  const float rl = 1.f / l;
  unsigned o[4];
  #pragma unroll
  for (int q = 0; q < 4; ++q){
    const int c0 = p*8 + 2*q, c1 = c0 + 1;
    float v0 = fmaxf(acc[2*q]*rl + ldf(bias,c0,isbf), 0.f);
    v0 = (v0 - ldf(bnm,c0,isbf)) * rsqrtf(ldf(bnv,c0,isbf) + BN_EPS) * ldf(bng,c0,isbf) + ldf(bnb,c0,isbf);
    float v1 = fmaxf(acc[2*q+1]*rl + ldf(bias,c1,isbf), 0.f);
    v1 = (v1 - ldf(bnm,c1,isbf)) * rsqrtf(ldf(bnv,c1,isbf) + BN_EPS) * ldf(bng,c1,isbf) + ldf(bnb,c1,isbf);
    o[q] = pk(v0, v1);
  }
  *((uint4*)(Hout + (size_t)node*64 + p*4)) = make_uint4(o[0], o[1], o[2], o[3]);
}

// ---------------- aggregation (layer 3) + log_softmax (1 node/wave) -----------
__global__ __launch_bounds__(256) void agg1(
    const unsigned* __restrict__ H3,
    const float* __restrict__ AL, const float* __restrict__ AD,
    const int* __restrict__ cnt, const int* __restrict__ start, const int* __restrict__ col,
    const void* __restrict__ b3, const int* __restrict__ flagp,
    void* __restrict__ out, int n)
{
  const int isbf = *flagp;
  const int wave = threadIdx.x >> 6;
  const int lane = threadIdx.x & 63;
  const int node = blockIdx.x*4 + wave;
  if (node >= n) return;
  const float ad = AD[node];
  const bool act = lane < 20;
  const int base = start[node], deg = cnt[node];

  float accL, accH, l;
  {
    float e = __expf(lrelu(AL[node] + ad));
    unsigned h = act ? H3[(size_t)node*20 + lane] : 0u;
    l = e; accL = e * bflo(h); accH = e * bfhi(h);
  }

  int i = 0;
  for (; i + 8 <= deg; i += 8){
    int sv[8]; float av[8]; unsigned hv[8];
    #pragma unroll
    for (int u = 0; u < 8; ++u){
      int s = col[base + i + u];
      sv[u] = ((unsigned)s < (unsigned)n) ? s : 0;
    }
    #pragma unroll
    for (int u = 0; u < 8; ++u) av[u] = AL[sv[u]];
    #pragma unroll
    for (int u = 0; u < 8; ++u) hv[u] = act ? H3[(size_t)sv[u]*20 + lane] : 0u;
    #pragma unroll
    for (int u = 0; u < 8; ++u){
      float e = __expf(lrelu(av[u] + ad));
      l    += e;
      accL += e * bflo(hv[u]);
      accH += e * bfhi(hv[u]);
    }
  }
  for (; i < deg; ++i){
    int s = col[base + i];
    if ((unsigned)s >= (unsigned)n) s = 0;
    float a = AL[s];
    unsigned h = act ? H3[(size_t)s*20 + lane] : 0u;
    float e = __expf(lrelu(a + ad));
    l += e; accL += e * bflo(h); accH += e * bfhi(h);
  }

  const float rl = 1.f / l;
  const int c0 = 2*lane;
  float z0 = act ? (accL*rl + ldf(b3, c0,     isbf)) : NEGBIG;
  float z1 = act ? (accH*rl + ldf(b3, c0 + 1, isbf)) : NEGBIG;
  float mx = fmaxf(z0, z1);
  #pragma unroll
  for (int off = 1; off < 64; off <<= 1) mx = fmaxf(mx, __shfl_xor(mx, off));
  float pp = act ? (__expf(z0 - mx) + __expf(z1 - mx)) : 0.f;
  float sum = pp;
  #pragma unroll
  for (int off = 1; off < 64; off <<= 1) sum += __shfl_xor(sum, off);
  if (act){
    float lg = __logf(sum);
    float r0 = z0 - mx - lg, r1 = z1 - mx - lg;
    if (isbf) ((unsigned*)out)[(size_t)node*20 + lane] = pk(r0, r1);
    else      ((float2*)out)[(size_t)node*20 + lane] = make_float2(r0, r1);
  }
}

// ---------------- launch ----------------
extern "C" void kernel_launch(void* const* d_in, const int* in_sizes, int n_in,
                              void* d_out, int out_size, void* d_ws, size_t ws_size,
                              hipStream_t stream)
{
  (void)n_in; (void)out_size; (void)ws_size;
  const void* x    = d_in[0];
  const int*  ei   = (const int*)d_in[1];
  const void* W1   = d_in[2];
  const void* as1  = d_in[3];
  const void* ad1  = d_in[4];
  const void* b1   = d_in[5];
  const void* W2   = d_in[6];
  const void* as2  = d_in[7];
  const void* ad2  = d_in[8];
  const void* b2   = d_in[9];
  const void* W3   = d_in[10];
  const void* as3  = d_in[11];
  const void* ad3  = d_in[12];
  const void* b3   = d_in[13];
  const void* bn1g = d_in[14];
  const void* bn1b = d_in[15];
  const void* bn1m = d_in[16];
  const void* bn1v = d_in[17];
  const void* bn2g = d_in[18];
  const void* bn2b = d_in[19];
  const void* bn2m = d_in[20];
  const void* bn2v = d_in[21];

  const int N  = in_sizes[0] / 128;
  const int E  = in_sizes[1] / 2;
  const int ntiles = (N + 15) / 16;

  char* w = (char*)d_ws;
  size_t off = 0;
  auto alloc = [&](size_t bytes)->char*{
    char* p = w + off; off = (off + bytes + 255) & ~(size_t)255; return p;
  };
  unsigned* H2A = (unsigned*)alloc((size_t)N*64*4);   // packed bf16 pairs
  unsigned* H2B = (unsigned*)alloc((size_t)N*64*4);
  unsigned* H3p = (unsigned*)alloc((size_t)N*20*4);
  float* AL   = (float*)alloc((size_t)N*4*4);
  float* AD   = (float*)alloc((size_t)N*4*4);
  int*   cnt   = (int*)alloc((size_t)N*4);
  int*   start = (int*)alloc((size_t)N*4);
  int*   pos   = (int*)alloc((size_t)N*4);
  int*   col   = (int*)alloc((size_t)E*4);
  int*   flag  = (int*)alloc(256);
  int*   total = (int*)alloc(256);

  const int* srcp = ei;
  const int* dstp = ei + E;

  const int nb256 = (N + 255)/256, eb256 = (E + 255)/256;
  const int bb = (N + 3)/4;        // 1 node per wave, 4 waves per block
  int g1 = ntiles < 625 ? ntiles : 625;
  int g3 = (ntiles + 3)/4; if (g3 > 400) g3 = 400;

  // CSR build via counting sort (no pointer-chase passes)
  init_detect<<<nb256,256,0,stream>>>(cnt, (const unsigned short*)W1, flag, total, N);
  hist<<<eb256,256,0,stream>>>(dstp, cnt, E, N);
  csr_scan<<<nb256,256,0,stream>>>(cnt, start, pos, total, N);
  scatter<<<eb256,256,0,stream>>>(srcp, dstp, pos, col, E, N);

  // layer 1
  gemm_al_mfma<<<g1,256,0,stream>>>(x, 0, W1, as1, ad1, flag, H2A, AL, AD, N, ntiles);
  agg4<<<bb,256,0,stream>>>(H2A, AL, AD, cnt, start, col,
                            b1, bn1g, bn1b, bn1m, bn1v, flag, H2B, N);
  // layer 2
  gemm_al_mfma<<<g1,256,0,stream>>>(H2B, 1, W2, as2, ad2, flag, H2A, AL, AD, N, ntiles);
  agg4<<<bb,256,0,stream>>>(H2A, AL, AD, cnt, start, col,
                            b2, bn2g, bn2b, bn2m, bn2v, flag, H2B, N);
  // layer 3
  gemm3_mfma<<<g3,256,0,stream>>>(H2B, W3, as3, ad3, flag, H3p, AL, AD, N, ntiles);
  agg1<<<bb,256,0,stream>>>(H3p, AL, AD, cnt, start, col, b3, flag, d_out, N);
}

// Round 3
// 457.795 us; speedup vs baseline: 1.0464x; 1.0464x over previous
//
#include <hip/hip_runtime.h>
#include <hip/hip_bf16.h>
#include <math.h>

using bf16 = __hip_bfloat16;
using frag8 = __attribute__((ext_vector_type(8))) short;
using f32x4 = __attribute__((ext_vector_type(4))) float;

#define LEAKY 0.2f
#define BN_EPS 1e-5f
#define NEGBIG -1e30f

__device__ __forceinline__ float lrelu(float z){ return fmaxf(z, LEAKY * z); }
__device__ __forceinline__ float bflo(unsigned u){ return __uint_as_float(u << 16); }
__device__ __forceinline__ float bfhi(unsigned u){ return __uint_as_float(u & 0xffff0000u); }
// pack two floats into bf16 pair (RNE)
__device__ __forceinline__ unsigned pk(float a, float b){
  unsigned ua = __float_as_uint(a), ub = __float_as_uint(b);
  ua += 0x7fffu + ((ua >> 16) & 1u);
  ub += 0x7fffu + ((ub >> 16) & 1u);
  return (ua >> 16) | (ub & 0xffff0000u);
}
// dtype-adaptive load: isbf=1 -> bf16, else fp32
__device__ __forceinline__ float ldf(const void* p, size_t i, int isbf){
  if (isbf) return (float)((const bf16*)p)[i];
  return ((const float*)p)[i];
}

union U4F8 { uint4 u; frag8 f; };

// A-frag loaders: lane m=lane&15 -> node, k0 = s*32 + quad*8, 8 bf16 = 16B
__device__ __forceinline__ frag8 load_a_pairs(const unsigned* __restrict__ X2, int node, int k0){
  U4F8 v; v.u = *((const uint4*)(X2 + (size_t)node*64 + (k0 >> 1))); return v.f;
}
__device__ __forceinline__ frag8 load_a_f32(const float* __restrict__ X, int node, int k0){
  float4 q0 = *((const float4*)(X + (size_t)node*128 + k0));
  float4 q1 = *((const float4*)(X + (size_t)node*128 + k0 + 4));
  U4F8 v; v.u = make_uint4(pk(q0.x,q0.y), pk(q0.z,q0.w), pk(q1.x,q1.y), pk(q1.z,q1.w));
  return v.f;
}

// ------------- cnt zero + total zero + fused input-dtype detector (block 0) ---
__global__ void init_detect(int* cnt, const unsigned short* __restrict__ w1bits,
                            int* flag, int* total, int n){
  int g = blockIdx.x*256 + threadIdx.x;
  if (g < n) cnt[g] = 0;
  if (g == 0) *total = 0;
  if (blockIdx.x == 0){
    __shared__ int cntr;
    if (threadIdx.x == 0) cntr = 0;
    __syncthreads();
    unsigned u = w1bits[threadIdx.x * 2];
    int e = (u >> 7) & 0xff;
    atomicAdd(&cntr, (e >= 64 && e <= 140) ? 1 : 0);
    __syncthreads();
    if (threadIdx.x == 0) *flag = (cntr >= 160) ? 1 : 0;
  }
}

// ------------- degree histogram: coalesced dst read, L2-hot atomics -----------
__global__ void hist(const int* __restrict__ dst, int* cnt, int e, int n){
  int g = blockIdx.x*256 + threadIdx.x;
  if (g < e){
    int d = dst[g];
    if ((unsigned)d < (unsigned)n) atomicAdd(&cnt[d], 1);
  }
}

// ------------- block-scan -> start offsets (order-free segments) + cursor -----
__global__ void csr_scan(const int* __restrict__ cnt, int* start, int* pos,
                         int* total, int n){
  __shared__ int s[256];
  __shared__ int base_s;
  int t = threadIdx.x;
  int g = blockIdx.x*256 + t;
  int v = (g < n) ? cnt[g] : 0;
  s[t] = v;
  __syncthreads();
  for (int off = 1; off < 256; off <<= 1){
    int x = (t >= off) ? s[t-off] : 0;
    __syncthreads();
    s[t] += x;
    __syncthreads();
  }
  if (t == 255) base_s = atomicAdd(total, s[255]);
  __syncthreads();
  if (g < n){
    int st = base_s + s[t] - v;
    start[g] = st;
    pos[g] = st;
  }
}

// ------------- direct scatter: coalesced reads, one int2 scattered write ------
__global__ void scatter(const int* __restrict__ src, const int* __restrict__ dst,
                        int* pos, int2* col2, int e, int n){
  int g = blockIdx.x*256 + threadIdx.x;
  if (g < e){
    int d = dst[g];
    if ((unsigned)d < (unsigned)n){
      int p = atomicAdd(&pos[d], 1);
      col2[p] = make_int2(src[g], d);
    }
  }
}

// ------------- edge weights (layers 1,2): w[p][h] = exp(lrelu(AL[s]+AD[d])) ---
__global__ void edgew4(const int2* __restrict__ col2,
                       const float* __restrict__ AL, const float* __restrict__ AD,
                       const int* __restrict__ totalp, float* __restrict__ wgt){
  int g = blockIdx.x*256 + threadIdx.x;
  if (g >= *totalp) return;
  int2 sd = col2[g];
  float4 a = *((const float4*)(AL + sd.x*4));
  float4 b = *((const float4*)(AD + sd.y*4));
  float4 o;
  o.x = __expf(lrelu(a.x + b.x));
  o.y = __expf(lrelu(a.y + b.y));
  o.z = __expf(lrelu(a.z + b.z));
  o.w = __expf(lrelu(a.w + b.w));
  *((float4*)(wgt + g*4)) = o;
}

// ------------- edge weights (layer 3, single head) ----------------------------
__global__ void edgew1(const int2* __restrict__ col2,
                       const float* __restrict__ AL, const float* __restrict__ AD,
                       const int* __restrict__ totalp, float* __restrict__ wgt){
  int g = blockIdx.x*256 + threadIdx.x;
  if (g >= *totalp) return;
  int2 sd = col2[g];
  wgt[g] = __expf(lrelu(AL[sd.x] + AD[sd.y]));
}

// ---------------- MFMA GEMM 128x128 + fused al (layers 1,2) --------------------
__global__ __launch_bounds__(256) void gemm_al_mfma(
    const void* __restrict__ X, int xkind,   // 0 = external input, 1 = packed pairs
    const void* __restrict__ W, const void* __restrict__ Wsrc, const void* __restrict__ Wdst,
    const int* __restrict__ flagp,
    unsigned* __restrict__ H2, float* __restrict__ AL, float* __restrict__ AD,
    int n, int ntiles)
{
  __shared__ unsigned short WT[128*136];   // W^T bf16, stride 136 (bank-stagger)
  const int isbf = *flagp;
  const int t = threadIdx.x;
  if (isbf){
    const unsigned short* W16 = (const unsigned short*)W;
    for (int idx = t; idx < 16384; idx += 256){
      int k = idx >> 7, nn = idx & 127;
      WT[nn*136 + k] = W16[idx];
    }
  } else {
    const float* Wf = (const float*)W;
    for (int idx = t; idx < 16384; idx += 256){
      int k = idx >> 7, nn = idx & 127;
      WT[nn*136 + k] = (unsigned short)(pk(Wf[idx], 0.f) & 0xffffu);
    }
  }
  __syncthreads();
  const int w = t >> 6;          // wave == head
  const int lane = t & 63;
  const int m = lane & 15, quad = lane >> 4;

  frag8 bf[4][2];
  #pragma unroll
  for (int s = 0; s < 4; ++s)
    #pragma unroll
    for (int ct = 0; ct < 2; ++ct){
      int colc = w*32 + ct*16 + m;
      int k0 = s*32 + quad*8;
      U4F8 v; v.u = *((const uint4*)&WT[colc*136 + k0]);
      bf[s][ct] = v.f;
    }
  float avv[2], dvv[2];
  #pragma unroll
  for (int ct = 0; ct < 2; ++ct){
    int colc = w*32 + ct*16 + m;
    avv[ct] = ldf(Wsrc, colc, isbf);
    dvv[ct] = ldf(Wdst, colc, isbf);
  }
  const bool pairs = (xkind == 1) || isbf;  // bf16 rows == packed-pair layout

  for (int tile = blockIdx.x; tile < ntiles; tile += gridDim.x){
    const int mb = tile*16;
    int nodeA = mb + m; if (nodeA >= n) nodeA = n - 1;
    frag8 af[4];
    #pragma unroll
    for (int s = 0; s < 4; ++s){
      int k0 = s*32 + quad*8;
      af[s] = pairs ? load_a_pairs((const unsigned*)X, nodeA, k0)
                    : load_a_f32((const float*)X, nodeA, k0);
    }
    f32x4 acc0 = {0.f,0.f,0.f,0.f}, acc1 = {0.f,0.f,0.f,0.f};
    #pragma unroll
    for (int s = 0; s < 4; ++s){
      acc0 = __builtin_amdgcn_mfma_f32_16x16x32_bf16(af[s], bf[s][0], acc0, 0,0,0);
      acc1 = __builtin_amdgcn_mfma_f32_16x16x32_bf16(af[s], bf[s][1], acc1, 0,0,0);
    }
    #pragma unroll
    for (int r = 0; r < 4; ++r){
      int g = mb + quad*4 + r;
      float v0 = acc0[r], v1 = acc1[r];
      unsigned u0 = pk(v0, __shfl_xor(v0, 1));
      unsigned u1 = pk(v1, __shfl_xor(v1, 1));
      bool ok = g < n;
      if (((lane & 1) == 0) && ok){
        H2[(size_t)g*64 + w*16 + (m >> 1)]     = u0;
        H2[(size_t)g*64 + w*16 + 8 + (m >> 1)] = u1;
      }
      float s1 = v0*avv[0] + v1*avv[1];
      float s2 = v0*dvv[0] + v1*dvv[1];
      s1 += __shfl_xor(s1,1); s1 += __shfl_xor(s1,2); s1 += __shfl_xor(s1,4); s1 += __shfl_xor(s1,8);
      s2 += __shfl_xor(s2,1); s2 += __shfl_xor(s2,2); s2 += __shfl_xor(s2,4); s2 += __shfl_xor(s2,8);
      if (m == 0 && ok){ AL[g*4 + w] = s1; AD[g*4 + w] = s2; }
    }
  }
}

// ---------------- MFMA GEMM 128x40 + fused al (layer 3) -----------------------
// H3 stored with stride 32 words (128B row) for 1-instr gather addressing.
__global__ __launch_bounds__(256) void gemm3_mfma(
    const unsigned* __restrict__ X2, const void* __restrict__ W,
    const void* __restrict__ Wsrc, const void* __restrict__ Wdst,
    const int* __restrict__ flagp,
    unsigned* __restrict__ H3, float* __restrict__ AL, float* __restrict__ AD,
    int n, int ntiles)
{
  __shared__ unsigned short WT[48*136];
  const int isbf = *flagp;
  const int t = threadIdx.x;
  for (int idx = t; idx < 128*64; idx += 256){
    int c = idx & 63, k = idx >> 6;
    if (c < 48){
      unsigned short v = 0;
      if (c < 40){
        if (isbf) v = ((const unsigned short*)W)[k*40 + c];
        else      v = (unsigned short)(pk(((const float*)W)[k*40 + c], 0.f) & 0xffffu);
      }
      WT[c*136 + k] = v;
    }
  }
  __syncthreads();
  const int w = t >> 6;
  const int lane = t & 63;
  const int m = lane & 15, quad = lane >> 4;

  frag8 bf[4][3];
  float avv[3], dvv[3];
  #pragma unroll
  for (int ct = 0; ct < 3; ++ct){
    int colc = ct*16 + m;
    #pragma unroll
    for (int s = 0; s < 4; ++s){
      int k0 = s*32 + quad*8;
      U4F8 v; v.u = *((const uint4*)&WT[colc*136 + k0]);
      bf[s][ct] = v.f;
    }
    avv[ct] = (colc < 40) ? ldf(Wsrc, colc, isbf) : 0.f;
    dvv[ct] = (colc < 40) ? ldf(Wdst, colc, isbf) : 0.f;
  }

  for (int tg = blockIdx.x; tg*4 < ntiles; tg += gridDim.x){
    const int tile = tg*4 + w;
    if (tile >= ntiles) continue;
    const int mb = tile*16;
    int nodeA = mb + m; if (nodeA >= n) nodeA = n - 1;
    frag8 af[4];
    #pragma unroll
    for (int s = 0; s < 4; ++s)
      af[s] = load_a_pairs(X2, nodeA, s*32 + quad*8);
    f32x4 acc[3];
    #pragma unroll
    for (int ct = 0; ct < 3; ++ct) acc[ct] = (f32x4){0.f,0.f,0.f,0.f};
    #pragma unroll
    for (int s = 0; s < 4; ++s){
      acc[0] = __builtin_amdgcn_mfma_f32_16x16x32_bf16(af[s], bf[s][0], acc[0], 0,0,0);
      acc[1] = __builtin_amdgcn_mfma_f32_16x16x32_bf16(af[s], bf[s][1], acc[1], 0,0,0);
      acc[2] = __builtin_amdgcn_mfma_f32_16x16x32_bf16(af[s], bf[s][2], acc[2], 0,0,0);
    }
    #pragma unroll
    for (int r = 0; r < 4; ++r){
      int g = mb + quad*4 + r;
      bool ok = g < n;
      float ps = 0.f, pd = 0.f;
      #pragma unroll
      for (int ct = 0; ct < 3; ++ct){
        float v = acc[ct][r];
        ps += v*avv[ct]; pd += v*dvv[ct];
        unsigned u = pk(v, __shfl_xor(v, 1));
        bool stok = ((lane & 1) == 0) && ok && (ct < 2 || m < 8);
        if (stok) H3[(size_t)g*32 + ct*8 + (m >> 1)] = u;
      }
      ps += __shfl_xor(ps,1); ps += __shfl_xor(ps,2); ps += __shfl_xor(ps,4); ps += __shfl_xor(ps,8);
      pd += __shfl_xor(pd,1); pd += __shfl_xor(pd,2); pd += __shfl_xor(pd,4); pd += __shfl_xor(pd,8);
      if (m == 0 && ok){ AL[g] = ps; AD[g] = pd; }
    }
  }
}

// ---- aggregation (layers 1,2): 1 node/wave, precomputed w, pipelined 16-wide --
__global__ __launch_bounds__(256) void agg4(
    const unsigned* __restrict__ H2, const float* __restrict__ wgt,
    const int2* __restrict__ col2,
    const float* __restrict__ ALf, const float* __restrict__ ADf,
    const int* __restrict__ cnt, const int* __restrict__ start,
    const void* __restrict__ bias, const void* __restrict__ bng, const void* __restrict__ bnb,
    const void* __restrict__ bnm,  const void* __restrict__ bnv,
    const int* __restrict__ flagp,
    unsigned* __restrict__ Hout, int n)
{
  const int isbf = *flagp;
  const int wave = threadIdx.x >> 6;
  const int lane = threadIdx.x & 63;
  const int node = blockIdx.x*4 + wave;
  if (node >= n) return;
  const int head = lane >> 4;
  const int base = start[node], deg = cnt[node];

  float l, accL, accH;
  {
    float e = __expf(lrelu(ALf[node*4 + head] + ADf[node*4 + head]));  // self loop
    unsigned h = H2[node*64 + lane];
    l = e; accL = e*bflo(h); accH = e*bfhi(h);
  }

  const int nb = deg >> 4, rem = deg & 15;
  int sv[16];
  if (nb){
    #pragma unroll
    for (int u = 0; u < 16; ++u) sv[u] = col2[base + u].x;
    for (int b = 0; b < nb; ++b){
      const int i = b << 4;
      const int wbase = (base + i)*4 + head;
      float wv[16]; unsigned hv[16];
      #pragma unroll
      for (int u = 0; u < 16; ++u) wv[u] = wgt[wbase + u*4];
      #pragma unroll
      for (int u = 0; u < 16; ++u) hv[u] = H2[(sv[u] << 6) + lane];
      // prefetch next block's col (sv dead after hv address formation)
      if (b + 1 < nb){
        #pragma unroll
        for (int u = 0; u < 16; ++u) sv[u] = col2[base + i + 16 + u].x;
      } else if (rem){
        const int lim = rem - 1;
        #pragma unroll
        for (int u = 0; u < 16; ++u) sv[u] = col2[base + nb*16 + (u < lim ? u : lim)].x;
      }
      #pragma unroll
      for (int u = 0; u < 16; ++u){
        l += wv[u];
        accL = fmaf(wv[u], bflo(hv[u]), accL);
        accH = fmaf(wv[u], bfhi(hv[u]), accH);
      }
    }
  } else if (rem){
    const int lim = rem - 1;
    #pragma unroll
    for (int u = 0; u < 16; ++u) sv[u] = col2[base + (u < lim ? u : lim)].x;
  }
  if (rem){
    const int i = nb << 4;
    const int wbase = (base + i)*4 + head;
    const int lim = rem - 1;
    #pragma unroll
    for (int u = 0; u < 16; ++u){
      const bool v = u < rem;
      float wq = wgt[wbase + (u < lim ? u : lim)*4];
      unsigned hq = H2[(sv[u] << 6) + lane];
      float wm = v ? wq : 0.f;
      l += wm;
      accL = fmaf(wm, bflo(hq), accL);
      accH = fmaf(wm, bfhi(hq), accH);
    }
  }

  const float rl = 1.f / l;
  const int c0 = 2*lane, c1 = c0 + 1;
  float v0 = fmaxf(accL*rl + ldf(bias,c0,isbf), 0.f);
  v0 = (v0 - ldf(bnm,c0,isbf)) * rsqrtf(ldf(bnv,c0,isbf) + BN_EPS) * ldf(bng,c0,isbf) + ldf(bnb,c0,isbf);
  float v1 = fmaxf(accH*rl + ldf(bias,c1,isbf), 0.f);
  v1 = (v1 - ldf(bnm,c1,isbf)) * rsqrtf(ldf(bnv,c1,isbf) + BN_EPS) * ldf(bng,c1,isbf) + ldf(bnb,c1,isbf);
  Hout[node*64 + lane] = pk(v0, v1);
}

// ---- aggregation (layer 3) + log_softmax: precomputed w, pipelined 16-wide ----
__global__ __launch_bounds__(256) void agg1(
    const unsigned* __restrict__ H3, const float* __restrict__ wgt,
    const int2* __restrict__ col2,
    const float* __restrict__ AL, const float* __restrict__ AD,
    const int* __restrict__ cnt, const int* __restrict__ start,
    const void* __restrict__ b3, const int* __restrict__ flagp,
    void* __restrict__ out, int n)
{
  const int isbf = *flagp;
  const int wave = threadIdx.x >> 6;
  const int lane = threadIdx.x & 63;
  const int node = blockIdx.x*4 + wave;
  if (node >= n) return;
  const bool act = lane < 20;
  const int base = start[node], deg = cnt[node];

  float l, accL, accH;
  {
    float e = __expf(lrelu(AL[node] + AD[node]));
    unsigned h = act ? H3[node*32 + lane] : 0u;
    l = e; accL = e*bflo(h); accH = e*bfhi(h);
  }

  const int nb = deg >> 4, rem = deg & 15;
  int sv[16];
  if (nb){
    #pragma unroll
    for (int u = 0; u < 16; ++u) sv[u] = col2[base + u].x;
    for (int b = 0; b < nb; ++b){
      const int i = b << 4;
      float wv[16]; unsigned hv[16];
      #pragma unroll
      for (int u = 0; u < 16; ++u) wv[u] = wgt[base + i + u];
      #pragma unroll
      for (int u = 0; u < 16; ++u) hv[u] = act ? H3[(sv[u] << 5) + lane] : 0u;
      if (b + 1 < nb){
        #pragma unroll
        for (int u = 0; u < 16; ++u) sv[u] = col2[base + i + 16 + u].x;
      } else if (rem){
        const int lim = rem - 1;
        #pragma unroll
        for (int u = 0; u < 16; ++u) sv[u] = col2[base + nb*16 + (u < lim ? u : lim)].x;
      }
      #pragma unroll
      for (int u = 0; u < 16; ++u){
        l += wv[u];
        accL = fmaf(wv[u], bflo(hv[u]), accL);
        accH = fmaf(wv[u], bfhi(hv[u]), accH);
      }
    }
  } else if (rem){
    const int lim = rem - 1;
    #pragma unroll
    for (int u = 0; u < 16; ++u) sv[u] = col2[base + (u < lim ? u : lim)].x;
  }
  if (rem){
    const int i = nb << 4;
    const int lim = rem - 1;
    #pragma unroll
    for (int u = 0; u < 16; ++u){
      const bool v = u < rem;
      float wq = wgt[base + i + (u < lim ? u : lim)];
      unsigned hq = act ? H3[(sv[u] << 5) + lane] : 0u;
      float wm = v ? wq : 0.f;
      l += wm;
      accL = fmaf(wm, bflo(hq), accL);
      accH = fmaf(wm, bfhi(hq), accH);
    }
  }

  const float rl = 1.f / l;
  const int c0 = 2*lane;
  float z0 = act ? (accL*rl + ldf(b3, c0,     isbf)) : NEGBIG;
  float z1 = act ? (accH*rl + ldf(b3, c0 + 1, isbf)) : NEGBIG;
  float mx = fmaxf(z0, z1);
  #pragma unroll
  for (int off = 1; off < 64; off <<= 1) mx = fmaxf(mx, __shfl_xor(mx, off));
  float pp = act ? (__expf(z0 - mx) + __expf(z1 - mx)) : 0.f;
  float sum = pp;
  #pragma unroll
  for (int off = 1; off < 64; off <<= 1) sum += __shfl_xor(sum, off);
  if (act){
    float lg = __logf(sum);
    float r0 = z0 - mx - lg, r1 = z1 - mx - lg;
    if (isbf) ((unsigned*)out)[(size_t)node*20 + lane] = pk(r0, r1);
    else      ((float2*)out)[(size_t)node*20 + lane] = make_float2(r0, r1);
  }
}

// ---------------- launch ----------------
extern "C" void kernel_launch(void* const* d_in, const int* in_sizes, int n_in,
                              void* d_out, int out_size, void* d_ws, size_t ws_size,
                              hipStream_t stream)
{
  (void)n_in; (void)out_size; (void)ws_size;
  const void* x    = d_in[0];
  const int*  ei   = (const int*)d_in[1];
  const void* W1   = d_in[2];
  const void* as1  = d_in[3];
  const void* ad1  = d_in[4];
  const void* b1   = d_in[5];
  const void* W2   = d_in[6];
  const void* as2  = d_in[7];
  const void* ad2  = d_in[8];
  const void* b2   = d_in[9];
  const void* W3   = d_in[10];
  const void* as3  = d_in[11];
  const void* ad3  = d_in[12];
  const void* b3   = d_in[13];
  const void* bn1g = d_in[14];
  const void* bn1b = d_in[15];
  const void* bn1m = d_in[16];
  const void* bn1v = d_in[17];
  const void* bn2g = d_in[18];
  const void* bn2b = d_in[19];
  const void* bn2m = d_in[20];
  const void* bn2v = d_in[21];

  const int N  = in_sizes[0] / 128;
  const int E  = in_sizes[1] / 2;
  const int ntiles = (N + 15) / 16;

  char* w = (char*)d_ws;
  size_t off = 0;
  auto alloc = [&](size_t bytes)->char*{
    char* p = w + off; off = (off + bytes + 255) & ~(size_t)255; return p;
  };
  unsigned* H2A = (unsigned*)alloc((size_t)N*64*4);   // packed bf16 pairs
  unsigned* H2B = (unsigned*)alloc((size_t)N*64*4);
  unsigned* H3p = (unsigned*)alloc((size_t)N*32*4);   // stride-32 rows
  float* AL   = (float*)alloc((size_t)N*4*4);
  float* AD   = (float*)alloc((size_t)N*4*4);
  int*   cnt   = (int*)alloc((size_t)N*4);
  int*   start = (int*)alloc((size_t)N*4);
  int*   pos   = (int*)alloc((size_t)N*4);
  int2*  col2  = (int2*)alloc((size_t)E*8);
  float* wgt   = (float*)alloc((size_t)E*16);         // 4 heads (layer3 uses [0,E))
  int*   flag  = (int*)alloc(256);
  int*   total = (int*)alloc(256);

  const int* srcp = ei;
  const int* dstp = ei + E;

  const int nb256 = (N + 255)/256, eb256 = (E + 255)/256;
  const int bb = (N + 3)/4;        // 1 node per wave, 4 waves per block
  int g1 = ntiles < 625 ? ntiles : 625;
  int g3 = (ntiles + 3)/4; if (g3 > 400) g3 = 400;

  // CSR build via counting sort
  init_detect<<<nb256,256,0,stream>>>(cnt, (const unsigned short*)W1, flag, total, N);
  hist<<<eb256,256,0,stream>>>(dstp, cnt, E, N);
  csr_scan<<<nb256,256,0,stream>>>(cnt, start, pos, total, N);
  scatter<<<eb256,256,0,stream>>>(srcp, dstp, pos, col2, E, N);

  // layer 1
  gemm_al_mfma<<<g1,256,0,stream>>>(x, 0, W1, as1, ad1, flag, H2A, AL, AD, N, ntiles);
  edgew4<<<eb256,256,0,stream>>>(col2, AL, AD, total, wgt);
  agg4<<<bb,256,0,stream>>>(H2A, wgt, col2, AL, AD, cnt, start,
                            b1, bn1g, bn1b, bn1m, bn1v, flag, H2B, N);
  // layer 2
  gemm_al_mfma<<<g1,256,0,stream>>>(H2B, 1, W2, as2, ad2, flag, H2A, AL, AD, N, ntiles);
  edgew4<<<eb256,256,0,stream>>>(col2, AL, AD, total, wgt);
  agg4<<<bb,256,0,stream>>>(H2A, wgt, col2, AL, AD, cnt, start,
                            b2, bn2g, bn2b, bn2m, bn2v, flag, H2B, N);
  // layer 3
  gemm3_mfma<<<g3,256,0,stream>>>(H2B, W3, as3, ad3, flag, H3p, AL, AD, N, ntiles);
  edgew1<<<eb256,256,0,stream>>>(col2, AL, AD, total, wgt);
  agg1<<<bb,256,0,stream>>>(H3p, wgt, col2, AL, AD, cnt, start, b3, flag, d_out, N);
}

// Round 4
// 396.992 us; speedup vs baseline: 1.2067x; 1.1532x over previous
//
#include <hip/hip_runtime.h>
#include <hip/hip_bf16.h>
#include <math.h>

using bf16 = __hip_bfloat16;
using frag8 = __attribute__((ext_vector_type(8))) short;
using f32x4 = __attribute__((ext_vector_type(4))) float;

#define LEAKY 0.2f
#define BN_EPS 1e-5f
#define NEGBIG -1e30f
#define BSHIFT 9

__device__ __forceinline__ float lrelu(float z){ return fmaxf(z, LEAKY * z); }
__device__ __forceinline__ float bflo(unsigned u){ return __uint_as_float(u << 16); }
__device__ __forceinline__ float bfhi(unsigned u){ return __uint_as_float(u & 0xffff0000u); }
// pack two floats into bf16 pair (RNE)
__device__ __forceinline__ unsigned pk(float a, float b){
  unsigned ua = __float_as_uint(a), ub = __float_as_uint(b);
  ua += 0x7fffu + ((ua >> 16) & 1u);
  ub += 0x7fffu + ((ub >> 16) & 1u);
  return (ua >> 16) | (ub & 0xffff0000u);
}
// dtype-adaptive load: isbf=1 -> bf16, else fp32
__device__ __forceinline__ float ldf(const void* p, size_t i, int isbf){
  if (isbf) return (float)((const bf16*)p)[i];
  return ((const float*)p)[i];
}

union U4F8 { uint4 u; frag8 f; };

// A-frag loaders: lane m=lane&15 -> node, k0 = s*32 + quad*8, 8 bf16 = 16B
__device__ __forceinline__ frag8 load_a_pairs(const unsigned* __restrict__ X2, int node, int k0){
  U4F8 v; v.u = *((const uint4*)(X2 + (size_t)node*64 + (k0 >> 1))); return v.f;
}
__device__ __forceinline__ frag8 load_a_f32(const float* __restrict__ X, int node, int k0){
  float4 q0 = *((const float4*)(X + (size_t)node*128 + k0));
  float4 q1 = *((const float4*)(X + (size_t)node*128 + k0 + 4));
  U4F8 v; v.u = make_uint4(pk(q0.x,q0.y), pk(q0.z,q0.w), pk(q1.x,q1.y), pk(q1.z,q1.w));
  return v.f;
}

// ------------- cnt/bcnt/total zero + fused input-dtype detector (block 0) -----
__global__ void init_detect(int* cnt, int* bcnt, const unsigned short* __restrict__ w1bits,
                            int* flag, int* total, int n){
  int g = blockIdx.x*256 + threadIdx.x;
  if (g < n) cnt[g] = 0;
  if (g < 256) bcnt[g] = 0;
  if (g == 0) *total = 0;
  if (blockIdx.x == 0){
    __shared__ int cntr;
    if (threadIdx.x == 0) cntr = 0;
    __syncthreads();
    unsigned u = w1bits[threadIdx.x * 2];
    int e = (u >> 7) & 0xff;
    atomicAdd(&cntr, (e >= 64 && e <= 140) ? 1 : 0);
    __syncthreads();
    if (threadIdx.x == 0) *flag = (cntr >= 160) ? 1 : 0;
  }
}

// ------------- degree histogram + LDS-reduced bucket histogram ----------------
__global__ __launch_bounds__(256) void hist(const int* __restrict__ dst, int* cnt,
                                            int* bcnt, int e, int n){
  __shared__ int lb[256];
  const int t = threadIdx.x;
  lb[t] = 0;
  __syncthreads();
  const int c0 = blockIdx.x*4096;
  const int lim = min(4096, e - c0);
  for (int i = t; i < lim; i += 256){
    int d = dst[c0 + i];
    if ((unsigned)d < (unsigned)n){
      atomicAdd(&cnt[d], 1);
      atomicAdd(&lb[min(d >> BSHIFT, 255)], 1);
    }
  }
  __syncthreads();
  if (lb[t]) atomicAdd(&bcnt[t], lb[t]);
}

// ------------- block-scan -> start offsets (order-free segments) + cursor -----
__global__ void csr_scan(const int* __restrict__ cnt, int* start, int* pos,
                         int* total, int n){
  __shared__ int s[256];
  __shared__ int base_s;
  int t = threadIdx.x;
  int g = blockIdx.x*256 + t;
  int v = (g < n) ? cnt[g] : 0;
  s[t] = v;
  __syncthreads();
  for (int off = 1; off < 256; off <<= 1){
    int x = (t >= off) ? s[t-off] : 0;
    __syncthreads();
    s[t] += x;
    __syncthreads();
  }
  if (t == 255) base_s = atomicAdd(total, s[255]);
  __syncthreads();
  if (g < n){
    int st = base_s + s[t] - v;
    start[g] = st;
    pos[g] = st;
  }
}

// ------------- bucket scan (single block, <=256 buckets) ----------------------
__global__ void bscan(const int* __restrict__ bcnt, int* bstart, int* bpos){
  __shared__ int s[256];
  int t = threadIdx.x;
  int v = bcnt[t];
  s[t] = v;
  __syncthreads();
  for (int off = 1; off < 256; off <<= 1){
    int x = (t >= off) ? s[t-off] : 0;
    __syncthreads();
    s[t] += x;
    __syncthreads();
  }
  int st = s[t] - v;
  bstart[t] = st;
  bpos[t] = st;
}

// ------------- bucket sort pass: LDS counting sort of 4096-edge chunks --------
// writes (src,dst) bucket-contiguously into ebuf -> coalesced run-writes.
__global__ __launch_bounds__(256) void bsort(const int* __restrict__ src,
                                             const int* __restrict__ dst,
                                             int* bpos, int2* __restrict__ ebuf,
                                             int e, int n){
  __shared__ int lh[256], lo[256], gb[256];
  __shared__ int tot_s;
  __shared__ int2 buf[4096];
  const int t = threadIdx.x;
  const int c0 = blockIdx.x*4096;
  if (c0 >= e) return;
  const int lim = min(4096, e - c0);
  lh[t] = 0;
  __syncthreads();
  int2 ev[16]; int bk[16];
  #pragma unroll
  for (int j = 0; j < 16; ++j){
    const int i = j*256 + t;
    const bool valid = i < lim;
    int s = 0, d = 0;
    if (valid){ s = src[c0 + i]; d = dst[c0 + i]; }
    ev[j] = make_int2(s, d);
    bk[j] = (valid && (unsigned)d < (unsigned)n) ? min(d >> BSHIFT, 255) : -1;
    if (bk[j] >= 0) atomicAdd(&lh[bk[j]], 1);
  }
  __syncthreads();
  const int v = lh[t];
  lo[t] = v;
  __syncthreads();
  for (int off = 1; off < 256; off <<= 1){
    int x = (t >= off) ? lo[t-off] : 0;
    __syncthreads();
    lo[t] += x;
    __syncthreads();
  }
  if (t == 255) tot_s = lo[255];
  lo[t] -= v;                       // exclusive offset of bucket t in buf
  if (v) gb[t] = atomicAdd(&bpos[t], v);  // reserve global run for bucket t
  lh[t] = 0;                        // reuse as cursor
  __syncthreads();
  #pragma unroll
  for (int j = 0; j < 16; ++j){
    if (bk[j] >= 0){
      int r = atomicAdd(&lh[bk[j]], 1);
      buf[lo[bk[j]] + r] = ev[j];
    }
  }
  __syncthreads();
  const int tot = tot_s;
  for (int i = t; i < tot; i += 256){
    int2 sd = buf[i];
    int b = min(sd.y >> BSHIFT, 255);
    ebuf[gb[b] + (i - lo[b])] = sd;
  }
}

// ------------- final scatter: one block per bucket, L2-local col window -------
__global__ __launch_bounds__(512) void cscat(const int2* __restrict__ ebuf,
                                             const int* __restrict__ bstart,
                                             const int* __restrict__ bpos,
                                             int* pos, int* __restrict__ col){
  const int b = blockIdx.x;
  const int s1 = bpos[b];
  for (int i = bstart[b] + threadIdx.x; i < s1; i += 512){
    int2 sd = ebuf[i];
    int p = atomicAdd(&pos[sd.y], 1);
    col[p] = sd.x;
  }
}

// ---------------- MFMA GEMM 128x128 + fused al (layers 1,2) --------------------
__global__ __launch_bounds__(256) void gemm_al_mfma(
    const void* __restrict__ X, int xkind,   // 0 = external input, 1 = packed pairs
    const void* __restrict__ W, const void* __restrict__ Wsrc, const void* __restrict__ Wdst,
    const int* __restrict__ flagp,
    unsigned* __restrict__ H2, float* __restrict__ AL, float* __restrict__ AD,
    int n, int ntiles)
{
  __shared__ unsigned short WT[128*136];   // W^T bf16, stride 136 (bank-stagger)
  const int isbf = *flagp;
  const int t = threadIdx.x;
  if (isbf){
    const unsigned short* W16 = (const unsigned short*)W;
    for (int idx = t; idx < 16384; idx += 256){
      int k = idx >> 7, nn = idx & 127;
      WT[nn*136 + k] = W16[idx];
    }
  } else {
    const float* Wf = (const float*)W;
    for (int idx = t; idx < 16384; idx += 256){
      int k = idx >> 7, nn = idx & 127;
      WT[nn*136 + k] = (unsigned short)(pk(Wf[idx], 0.f) & 0xffffu);
    }
  }
  __syncthreads();
  const int w = t >> 6;          // wave == head
  const int lane = t & 63;
  const int m = lane & 15, quad = lane >> 4;

  frag8 bf[4][2];
  #pragma unroll
  for (int s = 0; s < 4; ++s)
    #pragma unroll
    for (int ct = 0; ct < 2; ++ct){
      int colc = w*32 + ct*16 + m;
      int k0 = s*32 + quad*8;
      U4F8 v; v.u = *((const uint4*)&WT[colc*136 + k0]);
      bf[s][ct] = v.f;
    }
  float avv[2], dvv[2];
  #pragma unroll
  for (int ct = 0; ct < 2; ++ct){
    int colc = w*32 + ct*16 + m;
    avv[ct] = ldf(Wsrc, colc, isbf);
    dvv[ct] = ldf(Wdst, colc, isbf);
  }
  const bool pairs = (xkind == 1) || isbf;  // bf16 rows == packed-pair layout

  for (int tile = blockIdx.x; tile < ntiles; tile += gridDim.x){
    const int mb = tile*16;
    int nodeA = mb + m; if (nodeA >= n) nodeA = n - 1;
    frag8 af[4];
    #pragma unroll
    for (int s = 0; s < 4; ++s){
      int k0 = s*32 + quad*8;
      af[s] = pairs ? load_a_pairs((const unsigned*)X, nodeA, k0)
                    : load_a_f32((const float*)X, nodeA, k0);
    }
    f32x4 acc0 = {0.f,0.f,0.f,0.f}, acc1 = {0.f,0.f,0.f,0.f};
    #pragma unroll
    for (int s = 0; s < 4; ++s){
      acc0 = __builtin_amdgcn_mfma_f32_16x16x32_bf16(af[s], bf[s][0], acc0, 0,0,0);
      acc1 = __builtin_amdgcn_mfma_f32_16x16x32_bf16(af[s], bf[s][1], acc1, 0,0,0);
    }
    #pragma unroll
    for (int r = 0; r < 4; ++r){
      int g = mb + quad*4 + r;
      float v0 = acc0[r], v1 = acc1[r];
      unsigned u0 = pk(v0, __shfl_xor(v0, 1));
      unsigned u1 = pk(v1, __shfl_xor(v1, 1));
      bool ok = g < n;
      if (((lane & 1) == 0) && ok){
        H2[(size_t)g*64 + w*16 + (m >> 1)]     = u0;
        H2[(size_t)g*64 + w*16 + 8 + (m >> 1)] = u1;
      }
      float s1 = v0*avv[0] + v1*avv[1];
      float s2 = v0*dvv[0] + v1*dvv[1];
      s1 += __shfl_xor(s1,1); s1 += __shfl_xor(s1,2); s1 += __shfl_xor(s1,4); s1 += __shfl_xor(s1,8);
      s2 += __shfl_xor(s2,1); s2 += __shfl_xor(s2,2); s2 += __shfl_xor(s2,4); s2 += __shfl_xor(s2,8);
      if (m == 0 && ok){ AL[g*4 + w] = s1; AD[g*4 + w] = s2; }
    }
  }
}

// ---------------- MFMA GEMM 128x40 + fused al (layer 3) -----------------------
__global__ __launch_bounds__(256) void gemm3_mfma(
    const unsigned* __restrict__ X2, const void* __restrict__ W,
    const void* __restrict__ Wsrc, const void* __restrict__ Wdst,
    const int* __restrict__ flagp,
    unsigned* __restrict__ H3, float* __restrict__ AL, float* __restrict__ AD,
    int n, int ntiles)
{
  __shared__ unsigned short WT[48*136];
  const int isbf = *flagp;
  const int t = threadIdx.x;
  for (int idx = t; idx < 128*64; idx += 256){
    int c = idx & 63, k = idx >> 6;
    if (c < 48){
      unsigned short v = 0;
      if (c < 40){
        if (isbf) v = ((const unsigned short*)W)[k*40 + c];
        else      v = (unsigned short)(pk(((const float*)W)[k*40 + c], 0.f) & 0xffffu);
      }
      WT[c*136 + k] = v;
    }
  }
  __syncthreads();
  const int w = t >> 6;
  const int lane = t & 63;
  const int m = lane & 15, quad = lane >> 4;

  frag8 bf[4][3];
  float avv[3], dvv[3];
  #pragma unroll
  for (int ct = 0; ct < 3; ++ct){
    int colc = ct*16 + m;
    #pragma unroll
    for (int s = 0; s < 4; ++s){
      int k0 = s*32 + quad*8;
      U4F8 v; v.u = *((const uint4*)&WT[colc*136 + k0]);
      bf[s][ct] = v.f;
    }
    avv[ct] = (colc < 40) ? ldf(Wsrc, colc, isbf) : 0.f;
    dvv[ct] = (colc < 40) ? ldf(Wdst, colc, isbf) : 0.f;
  }

  for (int tg = blockIdx.x; tg*4 < ntiles; tg += gridDim.x){
    const int tile = tg*4 + w;
    if (tile >= ntiles) continue;
    const int mb = tile*16;
    int nodeA = mb + m; if (nodeA >= n) nodeA = n - 1;
    frag8 af[4];
    #pragma unroll
    for (int s = 0; s < 4; ++s)
      af[s] = load_a_pairs(X2, nodeA, s*32 + quad*8);
    f32x4 acc[3];
    #pragma unroll
    for (int ct = 0; ct < 3; ++ct) acc[ct] = (f32x4){0.f,0.f,0.f,0.f};
    #pragma unroll
    for (int s = 0; s < 4; ++s){
      acc[0] = __builtin_amdgcn_mfma_f32_16x16x32_bf16(af[s], bf[s][0], acc[0], 0,0,0);
      acc[1] = __builtin_amdgcn_mfma_f32_16x16x32_bf16(af[s], bf[s][1], acc[1], 0,0,0);
      acc[2] = __builtin_amdgcn_mfma_f32_16x16x32_bf16(af[s], bf[s][2], acc[2], 0,0,0);
    }
    #pragma unroll
    for (int r = 0; r < 4; ++r){
      int g = mb + quad*4 + r;
      bool ok = g < n;
      float ps = 0.f, pd = 0.f;
      #pragma unroll
      for (int ct = 0; ct < 3; ++ct){
        float v = acc[ct][r];
        ps += v*avv[ct]; pd += v*dvv[ct];
        unsigned u = pk(v, __shfl_xor(v, 1));
        bool stok = ((lane & 1) == 0) && ok && (ct < 2 || m < 8);
        if (stok) H3[(size_t)g*20 + ct*8 + (m >> 1)] = u;
      }
      ps += __shfl_xor(ps,1); ps += __shfl_xor(ps,2); ps += __shfl_xor(ps,4); ps += __shfl_xor(ps,8);
      pd += __shfl_xor(pd,1); pd += __shfl_xor(pd,2); pd += __shfl_xor(pd,4); pd += __shfl_xor(pd,8);
      if (m == 0 && ok){ AL[g] = ps; AD[g] = pd; }
    }
  }
}

// ---------------- aggregation (layers 1,2): wave/node, 8-wide edge unroll ------
__global__ __launch_bounds__(256) void agg4(
    const unsigned* __restrict__ H2,
    const float* __restrict__ ALf, const float* __restrict__ ADf,
    const int* __restrict__ cnt, const int* __restrict__ start, const int* __restrict__ col,
    const void* __restrict__ bias, const void* __restrict__ bng, const void* __restrict__ bnb,
    const void* __restrict__ bnm,  const void* __restrict__ bnv,
    const int* __restrict__ flagp,
    unsigned* __restrict__ Hout, int n)
{
  const int isbf = *flagp;
  const int wave = threadIdx.x >> 6;
  const int lane = threadIdx.x & 63;
  const int node = blockIdx.x*4 + wave;
  if (node >= n) return;
  const int head = lane >> 4;
  const float ad = ADf[node*4 + head];
  const int base = start[node], deg = cnt[node];

  float accL, accH, l;
  {
    float e = __expf(lrelu(ALf[node*4 + head] + ad));
    unsigned h = H2[(size_t)node*64 + lane];
    l = e; accL = e * bflo(h); accH = e * bfhi(h);
  }

  int i = 0;
  for (; i + 8 <= deg; i += 8){
    int sv[8]; float av[8]; unsigned hv[8];
    #pragma unroll
    for (int u = 0; u < 8; ++u){
      int s = col[base + i + u];
      sv[u] = ((unsigned)s < (unsigned)n) ? s : 0;
    }
    #pragma unroll
    for (int u = 0; u < 8; ++u) av[u] = ALf[sv[u]*4 + head];
    #pragma unroll
    for (int u = 0; u < 8; ++u) hv[u] = H2[(size_t)sv[u]*64 + lane];
    #pragma unroll
    for (int u = 0; u < 8; ++u){
      float e = __expf(lrelu(av[u] + ad));
      l    += e;
      accL += e * bflo(hv[u]);
      accH += e * bfhi(hv[u]);
    }
  }
  for (; i < deg; ++i){
    int s = col[base + i];
    if ((unsigned)s >= (unsigned)n) s = 0;
    float a = ALf[s*4 + head];
    unsigned h = H2[(size_t)s*64 + lane];
    float e = __expf(lrelu(a + ad));
    l += e; accL += e * bflo(h); accH += e * bfhi(h);
  }

  const float rl = 1.f / l;
  const int c0 = 2*lane, c1 = c0 + 1;
  float v0 = fmaxf(accL*rl + ldf(bias,c0,isbf), 0.f);
  v0 = (v0 - ldf(bnm,c0,isbf)) * rsqrtf(ldf(bnv,c0,isbf) + BN_EPS) * ldf(bng,c0,isbf) + ldf(bnb,c0,isbf);
  float v1 = fmaxf(accH*rl + ldf(bias,c1,isbf), 0.f);
  v1 = (v1 - ldf(bnm,c1,isbf)) * rsqrtf(ldf(bnv,c1,isbf) + BN_EPS) * ldf(bng,c1,isbf) + ldf(bnb,c1,isbf);
  Hout[(size_t)node*64 + lane] = pk(v0, v1);
}

// ---------------- aggregation (layer 3) + log_softmax -------------------------
__global__ __launch_bounds__(256) void agg1(
    const unsigned* __restrict__ H3,
    const float* __restrict__ AL, const float* __restrict__ AD,
    const int* __restrict__ cnt, const int* __restrict__ start, const int* __restrict__ col,
    const void* __restrict__ b3, const int* __restrict__ flagp,
    void* __restrict__ out, int n)
{
  const int isbf = *flagp;
  const int wave = threadIdx.x >> 6;
  const int lane = threadIdx.x & 63;
  const int node = blockIdx.x*4 + wave;
  if (node >= n) return;
  const float ad = AD[node];
  const bool act = lane < 20;
  const int base = start[node], deg = cnt[node];

  float accL, accH, l;
  {
    float e = __expf(lrelu(AL[node] + ad));
    unsigned h = act ? H3[(size_t)node*20 + lane] : 0u;
    l = e; accL = e * bflo(h); accH = e * bfhi(h);
  }

  int i = 0;
  for (; i + 8 <= deg; i += 8){
    int sv[8]; float av[8]; unsigned hv[8];
    #pragma unroll
    for (int u = 0; u < 8; ++u){
      int s = col[base + i + u];
      sv[u] = ((unsigned)s < (unsigned)n) ? s : 0;
    }
    #pragma unroll
    for (int u = 0; u < 8; ++u) av[u] = AL[sv[u]];
    #pragma unroll
    for (int u = 0; u < 8; ++u) hv[u] = act ? H3[(size_t)sv[u]*20 + lane] : 0u;
    #pragma unroll
    for (int u = 0; u < 8; ++u){
      float e = __expf(lrelu(av[u] + ad));
      l    += e;
      accL += e * bflo(hv[u]);
      accH += e * bfhi(hv[u]);
    }
  }
  for (; i < deg; ++i){
    int s = col[base + i];
    if ((unsigned)s >= (unsigned)n) s = 0;
    float a = AL[s];
    unsigned h = act ? H3[(size_t)s*20 + lane] : 0u;
    float e = __expf(lrelu(a + ad));
    l += e; accL += e * bflo(h); accH += e * bfhi(h);
  }

  const float rl = 1.f / l;
  const int c0 = 2*lane;
  float z0 = act ? (accL*rl + ldf(b3, c0,     isbf)) : NEGBIG;
  float z1 = act ? (accH*rl + ldf(b3, c0 + 1, isbf)) : NEGBIG;
  float mx = fmaxf(z0, z1);
  #pragma unroll
  for (int off = 1; off < 64; off <<= 1) mx = fmaxf(mx, __shfl_xor(mx, off));
  float p = act ? (__expf(z0 - mx) + __expf(z1 - mx)) : 0.f;
  float sum = p;
  #pragma unroll
  for (int off = 1; off < 64; off <<= 1) sum += __shfl_xor(sum, off);
  if (act){
    float lg = __logf(sum);
    float r0 = z0 - mx - lg, r1 = z1 - mx - lg;
    if (isbf) ((unsigned*)out)[(size_t)node*20 + lane] = pk(r0, r1);
    else      ((float2*)out)[(size_t)node*20 + lane] = make_float2(r0, r1);
  }
}

// ---------------- launch ----------------
extern "C" void kernel_launch(void* const* d_in, const int* in_sizes, int n_in,
                              void* d_out, int out_size, void* d_ws, size_t ws_size,
                              hipStream_t stream)
{
  (void)n_in; (void)out_size; (void)ws_size;
  const void* x    = d_in[0];
  const int*  ei   = (const int*)d_in[1];
  const void* W1   = d_in[2];
  const void* as1  = d_in[3];
  const void* ad1  = d_in[4];
  const void* b1   = d_in[5];
  const void* W2   = d_in[6];
  const void* as2  = d_in[7];
  const void* ad2  = d_in[8];
  const void* b2   = d_in[9];
  const void* W3   = d_in[10];
  const void* as3  = d_in[11];
  const void* ad3  = d_in[12];
  const void* b3   = d_in[13];
  const void* bn1g = d_in[14];
  const void* bn1b = d_in[15];
  const void* bn1m = d_in[16];
  const void* bn1v = d_in[17];
  const void* bn2g = d_in[18];
  const void* bn2b = d_in[19];
  const void* bn2m = d_in[20];
  const void* bn2v = d_in[21];

  const int N  = in_sizes[0] / 128;
  const int E  = in_sizes[1] / 2;
  const int ntiles = (N + 15) / 16;

  char* w = (char*)d_ws;
  size_t off = 0;
  auto alloc = [&](size_t bytes)->char*{
    char* p = w + off; off = (off + bytes + 255) & ~(size_t)255; return p;
  };
  unsigned* H2A = (unsigned*)alloc((size_t)N*64*4);   // packed bf16 pairs
  unsigned* H2B = (unsigned*)alloc((size_t)N*64*4);
  unsigned* H3p = (unsigned*)alloc((size_t)N*20*4);
  float* AL   = (float*)alloc((size_t)N*4*4);
  float* AD   = (float*)alloc((size_t)N*4*4);
  int*   cnt   = (int*)alloc((size_t)N*4);
  int*   start = (int*)alloc((size_t)N*4);
  int*   pos   = (int*)alloc((size_t)N*4);
  int*   col   = (int*)alloc((size_t)E*4);
  int2*  ebuf  = (int2*)alloc((size_t)E*8);
  int*   bcnt  = (int*)alloc(1024);
  int*   bstart= (int*)alloc(1024);
  int*   bpos  = (int*)alloc(1024);
  int*   flag  = (int*)alloc(256);
  int*   total = (int*)alloc(256);

  const int* srcp = ei;
  const int* dstp = ei + E;

  const int nb256 = (N + 255)/256;
  const int nbCH = (E + 4095)/4096;
  const int bb = (N + 3)/4;        // 1 node per wave, 4 waves per block
  int g1 = ntiles < 625 ? ntiles : 625;
  int g3 = (ntiles + 3)/4; if (g3 > 400) g3 = 400;

  // CSR build: counting sort with bucket-staged scatter (L2-local windows)
  init_detect<<<nb256,256,0,stream>>>(cnt, bcnt, (const unsigned short*)W1, flag, total, N);
  hist<<<nbCH,256,0,stream>>>(dstp, cnt, bcnt, E, N);
  csr_scan<<<nb256,256,0,stream>>>(cnt, start, pos, total, N);
  bscan<<<1,256,0,stream>>>(bcnt, bstart, bpos);
  bsort<<<nbCH,256,0,stream>>>(srcp, dstp, bpos, ebuf, E, N);
  cscat<<<256,512,0,stream>>>(ebuf, bstart, bpos, pos, col);

  // layer 1
  gemm_al_mfma<<<g1,256,0,stream>>>(x, 0, W1, as1, ad1, flag, H2A, AL, AD, N, ntiles);
  agg4<<<bb,256,0,stream>>>(H2A, AL, AD, cnt, start, col,
                            b1, bn1g, bn1b, bn1m, bn1v, flag, H2B, N);
  // layer 2
  gemm_al_mfma<<<g1,256,0,stream>>>(H2B, 1, W2, as2, ad2, flag, H2A, AL, AD, N, ntiles);
  agg4<<<bb,256,0,stream>>>(H2A, AL, AD, cnt, start, col,
                            b2, bn2g, bn2b, bn2m, bn2v, flag, H2B, N);
  // layer 3
  gemm3_mfma<<<g3,256,0,stream>>>(H2B, W3, as3, ad3, flag, H3p, AL, AD, N, ntiles);
  agg1<<<bb,256,0,stream>>>(H3p, AL, AD, cnt, start, col, b3, flag, d_out, N);
}